// Round 7
// baseline (116.038 us; speedup 1.0000x reference)
//
#include <hip/hip_runtime.h>
#include <math.h>

#define NN 8192

typedef __attribute__((ext_vector_type(8))) short short8;
typedef __attribute__((ext_vector_type(4))) short short4v;
typedef __attribute__((ext_vector_type(4))) float f32x4;
typedef __attribute__((ext_vector_type(4))) int int4v;

#define L2E 1.4426950408889634f

typedef __attribute__((address_space(3))) unsigned lds_u32;
typedef __attribute__((address_space(1))) unsigned g_u32;

__device__ __forceinline__ void gll16(const void* g, void* l) {
    __builtin_amdgcn_global_load_lds((const g_u32*)g, (lds_u32*)l, 16, 0, 0);
}

__device__ __forceinline__ short f2bf(float f) {
    union { float f; unsigned u; } v; v.f = f;
    unsigned r = v.u + 0x7fffu + ((v.u >> 16) & 1u);
    return (short)(r >> 16);
}

__device__ __forceinline__ f32x4 zero4() {
    f32x4 v; v[0] = 0.f; v[1] = 0.f; v[2] = 0.f; v[3] = 0.f; return v;
}

// ---------- K0: WT[f][k] = bf16(W[k][f]) ----------
__global__ void k0_wt(const float* __restrict__ W, short* __restrict__ WT) {
    int idx = blockIdx.x * 256 + threadIdx.x;
    if (idx < 256 * 128) {
        int k = idx & 255;
        int f = idx >> 8;
        WT[f * 256 + k] = f2bf(W[k * 128 + f]);
    }
}

// ---------- K1: h = x@W (bf16 MFMA); s1L2E/s2L2E; hT bf16 [128][8192] ----------
__global__ __launch_bounds__(128) void k1_h(
        const float* __restrict__ x, const short* __restrict__ WT,
        const float* __restrict__ a, short* __restrict__ hT,
        float* __restrict__ s1L2E, float* __restrict__ s2L2E) {
    const int w = threadIdx.x >> 6;
    const int l = threadIdx.x & 63;
    const int quad = l >> 4;
    const int fr = l & 15;
    const int i0 = blockIdx.x * 32 + w * 16;

    f32x4 acc[8];
#pragma unroll
    for (int t = 0; t < 8; ++t) acc[t] = zero4();

    const float* xrow = x + (size_t)(i0 + fr) * 256;
#pragma unroll
    for (int kk = 0; kk < 8; ++kk) {
        const int k0 = kk * 32 + quad * 8;
        f32x4 xa = *(const f32x4*)(xrow + k0);
        f32x4 xb = *(const f32x4*)(xrow + k0 + 4);
        short8 av;
#pragma unroll
        for (int e = 0; e < 4; ++e) { av[e] = f2bf(xa[e]); av[4 + e] = f2bf(xb[e]); }
#pragma unroll
        for (int t = 0; t < 8; ++t) {
            short8 bv = *(const short8*)(WT + (t * 16 + fr) * 256 + k0);
            acc[t] = __builtin_amdgcn_mfma_f32_16x16x32_bf16(av, bv, acc[t], 0, 0, 0);
        }
    }

    float s1p[4] = {0.f, 0.f, 0.f, 0.f};
    float s2p[4] = {0.f, 0.f, 0.f, 0.f};
#pragma unroll
    for (int t = 0; t < 8; ++t) {
        float a1v = a[t * 16 + fr];
        float a2v = a[128 + t * 16 + fr];
#pragma unroll
        for (int r = 0; r < 4; ++r) {
            s1p[r] += acc[t][r] * a1v;
            s2p[r] += acc[t][r] * a2v;
        }
    }
#pragma unroll
    for (int r = 0; r < 4; ++r) {
#pragma unroll
        for (int m = 1; m < 16; m <<= 1) {
            s1p[r] += __shfl_xor(s1p[r], m, 64);
            s2p[r] += __shfl_xor(s2p[r], m, 64);
        }
    }
    if (fr == 0) {
#pragma unroll
        for (int r = 0; r < 4; ++r) {
            const int i = i0 + quad * 4 + r;
            s1L2E[i] = s1p[r] * L2E;
            s2L2E[i] = s2p[r] * L2E;
        }
    }

#pragma unroll
    for (int t = 0; t < 8; ++t) {
        short4v hv;
#pragma unroll
        for (int r = 0; r < 4; ++r) hv[r] = f2bf(acc[t][r]);
        *(short4v*)(hT + (size_t)(t * 16 + fr) * NN + i0 + quad * 4) = hv;
    }
}

// ---------- K2: contiguity-optimized counted-vmcnt pipeline ----------
// 256 blocks (1/CU), 32 rows x 8192 cols each, 4 waves = 2 row-halves x 2 j.
// adj staged as 32x256-col MACRO tiles (32KB, 2-deep): each gll = ONE
// contiguous 1KB row-chunk (fixes the 256B/32KB-stride DRAM pattern that
// capped R6 at ~3 TB/s). hT staged at 64-col substeps (16KB, 4-deep).
// s2 strip (1KB/macro) rides the macro stage. vmcnt literals per substep
// residue: [12,21,21,21] (stage issued 4 substeps early; adj piggybacks
// every 4th). Never drains in-loop (T4).
// LDS: hbuf 4x16K @0 | abuf 2x32K @65536 | cbuf 2x1K @131072 | zbuf @133120.
__global__ __launch_bounds__(256, 1) void k2_attn(
        const int* __restrict__ adj, const short* __restrict__ hT,
        const float* __restrict__ s1g, const float* __restrict__ s2g,
        float* __restrict__ out) {
    constexpr int NSUB = NN / 64;      // 128 substeps
    constexpr int NMAC = NN / 256;     // 32 macros
    __shared__ __align__(16) char lds_c[133376];

    const int tid = threadIdx.x;
    const int w = tid >> 6;
    const int l = tid & 63;
    const int quad = l >> 4;
    const int fr = l & 15;
    const int rh = w >> 1;
    const int wj = w & 1;
    const int r32 = blockIdx.x * 32;

    const float S = s1g[r32 + rh * 16 + fr];   // s1*log2e for this lane's row

    // hT sources: pre-swizzled (phys = logical ^ ((row&7)<<4)), 128B/tile-row
    const char* hsrc[4];
    {
        const char* hbase = (const char*)hT;
#pragma unroll
        for (int p = 0; p < 4; ++p) {
            const int o = p * 4096 + tid * 16;
            const int row = o >> 7;
            const int colb = o & 127;
            hsrc[p] = hbase + (size_t)row * (NN * 2) + (colb ^ ((row & 7) << 4));
        }
    }
    // adj sources: one CONTIGUOUS 1KB row-chunk per gll; per-gll-uniform
    // chunk swizzle (lane reads logical chunk l^p so LDS slot l holds l^p).
    const char* asrc8[8];
    {
        const char* abase = (const char*)adj;
#pragma unroll
        for (int p = 0; p < 8; ++p) {
            const int row = w * 8 + p;                // row&7 == p
            asrc8[p] = abase + (size_t)(r32 + row) * (NN * 4) + ((l ^ p) << 4);
        }
    }
    const char* csrc = (const char*)s2g + l * 16;     // 1KB strip, all lanes

    auto STAGE_HT = [&](int q, int buf) {
        char* hd = lds_c + buf * 16384 + w * 1024;
        const size_t hof = (size_t)q * 128;
#pragma unroll
        for (int p = 0; p < 4; ++p) gll16(hsrc[p] + hof, hd + p * 4096);
    };
    auto STAGE_AC = [&](int m, int buf) {
        char* ad = lds_c + 65536 + buf * 32768 + w * 8192;
        const size_t aof = (size_t)m * 1024;
#pragma unroll
        for (int p = 0; p < 8; ++p) gll16(asrc8[p] + aof, ad + p * 1024);
        gll16(csrc + aof, lds_c + 131072 + buf * 1024);   // benign 4-wave WAW
    };

    f32x4 acc[8];
#pragma unroll
    for (int t = 0; t < 8; ++t) acc[t] = zero4();
    float zacc = 0.f;

    const int arow = rh * 16 + fr;
    const unsigned r7 = (unsigned)(arow & 7);

    auto COMPUTE = [&](int q) {
        const char* hb = lds_c + (q & 3) * 16384;
        const char* ab = lds_c + 65536 + ((q >> 2) & 1) * 32768;
        const float* cb = (const float*)(lds_c + 131072 + ((q >> 2) & 1) * 1024);
        const int sl = q & 3;

        const unsigned cch = (unsigned)(sl * 16 + wj * 8 + quad * 2);
        const int4v g0 = *(const int4v*)(ab + arow * 1024 + ((cch ^ r7) << 4));
        const int4v g1 = *(const int4v*)(ab + arow * 1024 + (((cch + 1) ^ r7) << 4));
        const f32x4 c0 = *(const f32x4*)(cb + sl * 64 + wj * 32 + quad * 8);
        const f32x4 c1 = *(const f32x4*)(cb + sl * 64 + wj * 32 + quad * 8 + 4);

        short8 pa;
        float zs = 0.f;
#pragma unroll
        for (int e = 0; e < 8; ++e) {
            const float cv = (e < 4) ? c0[e & 3] : c1[e & 3];
            const int gv = (e < 4) ? g0[e & 3] : g1[e & 3];
            const float u = S + cv;                 // (s1+s2)*log2e
            const float tt = fmaxf(u, 0.2f * u);    // leaky-relu in log2 space
            const float p = (gv > 0) ? exp2f(tt) : 0.f;
            zs += p;
            pa[e] = f2bf(p);
        }
        zacc += zs;

#pragma unroll
        for (int t8 = 0; t8 < 8; ++t8) {
            const int hrow = t8 * 16 + fr;
            const short8 bv = *(const short8*)(
                hb + ((unsigned)(hrow * 128 + wj * 64 + quad * 16) ^ ((hrow & 7) << 4)));
            acc[t8] = __builtin_amdgcn_mfma_f32_16x16x32_bf16(pa, bv, acc[t8], 0, 0, 0);
        }
    };

    // prologue: adj/c macro 0 (9 gll) + hT substeps 0..3 (16 gll) = 25 in flight
    STAGE_AC(0, 0);
    STAGE_HT(0, 0); STAGE_HT(1, 1); STAGE_HT(2, 2); STAGE_HT(3, 3);

#define SUBSTEP(S_, VMLIT)                                            \
    {                                                                 \
        asm volatile("s_waitcnt vmcnt(" #VMLIT ")" ::: "memory");     \
        __builtin_amdgcn_s_barrier();                                 \
        __builtin_amdgcn_sched_barrier(0);                            \
        COMPUTE(m * 4 + S_);                                          \
        __builtin_amdgcn_sched_barrier(0);                            \
        asm volatile("" ::: "memory");                                \
        __builtin_amdgcn_s_barrier();                                 \
        if (S_ == 0) {                                                \
            const int mm = (m + 1 < NMAC) ? m + 1 : NMAC - 1;         \
            STAGE_AC(mm, (m + 1) & 1);                                \
        }                                                             \
        {                                                             \
            int qq = m * 4 + S_ + 4;                                  \
            if (qq > NSUB - 1) qq = NSUB - 1;                         \
            STAGE_HT(qq, S_);                                         \
        }                                                             \
    }

    for (int m = 0; m < NMAC; ++m) {
        SUBSTEP(0, 12)
        SUBSTEP(1, 21)
        SUBSTEP(2, 21)
        SUBSTEP(3, 21)
    }
#undef SUBSTEP

    asm volatile("s_waitcnt vmcnt(0)" ::: "memory");  // drain junk tail stages
    __syncthreads();

    // ---- reduction (red aliases hbuf[0]; zbuf in its own slot) ----
    zacc += __shfl_xor(zacc, 16, 64);
    zacc += __shfl_xor(zacc, 32, 64);
    float* zb = (float*)(lds_c + 133120);
    if (l < 16) zb[w * 16 + l] = zacc;

    float* red = (float*)lds_c;   // 2 regions x 2048 floats (16KB)
    if (wj == 1) {
#pragma unroll
        for (int t = 0; t < 8; ++t)
            *(f32x4*)(red + rh * 2048 + t * 256 + l * 4) = acc[t];
    }
    __syncthreads();

    if (wj == 0) {
#pragma unroll
        for (int t = 0; t < 8; ++t)
            acc[t] += *(const f32x4*)(red + rh * 2048 + t * 256 + l * 4);
#pragma unroll
        for (int r = 0; r < 4; ++r) {
            const int irow = quad * 4 + r;
            const float z = zb[rh * 32 + irow] + zb[rh * 32 + 16 + irow];
            const int grow = r32 + rh * 16 + irow;
            const float inv = 1.0f / z;
            float* orow = out + (size_t)grow * 128;
#pragma unroll
            for (int t = 0; t < 8; ++t) {
                float v = acc[t][r] * inv;
                orow[t * 16 + fr] = (v > 0.f) ? v : expm1f(v);
            }
        }
    }
}

extern "C" void kernel_launch(void* const* d_in, const int* in_sizes, int n_in,
                              void* d_out, int out_size, void* d_ws, size_t ws_size,
                              hipStream_t stream) {
    const float* x   = (const float*)d_in[0];   // 8192 x 256
    const float* W   = (const float*)d_in[1];   // 256 x 128
    const float* a   = (const float*)d_in[2];   // 256
    const int*   adj = (const int*)d_in[3];     // 8192 x 8192
    float* out = (float*)d_out;                 // 8192 x 128

    char* ws = (char*)d_ws;
    const size_t MB = 1024 * 1024;
    short* hT    = (short*)ws;                        // 2 MB
    float* s1L2E = (float*)(ws + 2 * MB);             // 32 KB
    float* s2L2E = (float*)(ws + 2 * MB + 32768);     // 32 KB
    short* WT    = (short*)(ws + 2 * MB + 65536);     // 64 KB

    k0_wt<<<128, 256, 0, stream>>>(W, WT);
    k1_h<<<256, 128, 0, stream>>>(x, WT, a, hT, s1L2E, s2L2E);
    k2_attn<<<256, 256, 0, stream>>>(adj, hT, s1L2E, s2L2E, out);
}

// Round 8
// 102.202 us; speedup vs baseline: 1.1354x; 1.1354x over previous
//
#include <hip/hip_runtime.h>
#include <math.h>

#define NN 8192

typedef __attribute__((ext_vector_type(8))) short short8;
typedef __attribute__((ext_vector_type(4))) short short4v;
typedef __attribute__((ext_vector_type(4))) float f32x4;
typedef __attribute__((ext_vector_type(4))) int int4v;

#define L2E 1.4426950408889634f

typedef __attribute__((address_space(3))) unsigned lds_u32;
typedef __attribute__((address_space(1))) unsigned g_u32;

__device__ __forceinline__ void gll16(const void* g, void* l) {
    __builtin_amdgcn_global_load_lds((const g_u32*)g, (lds_u32*)l, 16, 0, 0);
}

__device__ __forceinline__ short f2bf(float f) {
    union { float f; unsigned u; } v; v.f = f;
    unsigned r = v.u + 0x7fffu + ((v.u >> 16) & 1u);
    return (short)(r >> 16);
}

__device__ __forceinline__ f32x4 zero4() {
    f32x4 v; v[0] = 0.f; v[1] = 0.f; v[2] = 0.f; v[3] = 0.f; return v;
}

// ---------- K0: WT[f][k] = bf16(W[k][f]) ----------
__global__ void k0_wt(const float* __restrict__ W, short* __restrict__ WT) {
    int idx = blockIdx.x * 256 + threadIdx.x;
    if (idx < 256 * 128) {
        int k = idx & 255;
        int f = idx >> 8;
        WT[f * 256 + k] = f2bf(W[k * 128 + f]);
    }
}

// ---------- K1: h = x@W (bf16 MFMA); s1L2E/s2L2E; hT bf16 [128][8192] ----------
__global__ __launch_bounds__(128) void k1_h(
        const float* __restrict__ x, const short* __restrict__ WT,
        const float* __restrict__ a, short* __restrict__ hT,
        float* __restrict__ s1L2E, float* __restrict__ s2L2E) {
    const int w = threadIdx.x >> 6;
    const int l = threadIdx.x & 63;
    const int quad = l >> 4;
    const int fr = l & 15;
    const int i0 = blockIdx.x * 32 + w * 16;

    f32x4 acc[8];
#pragma unroll
    for (int t = 0; t < 8; ++t) acc[t] = zero4();

    const float* xrow = x + (size_t)(i0 + fr) * 256;
#pragma unroll
    for (int kk = 0; kk < 8; ++kk) {
        const int k0 = kk * 32 + quad * 8;
        f32x4 xa = *(const f32x4*)(xrow + k0);
        f32x4 xb = *(const f32x4*)(xrow + k0 + 4);
        short8 av;
#pragma unroll
        for (int e = 0; e < 4; ++e) { av[e] = f2bf(xa[e]); av[4 + e] = f2bf(xb[e]); }
#pragma unroll
        for (int t = 0; t < 8; ++t) {
            short8 bv = *(const short8*)(WT + (t * 16 + fr) * 256 + k0);
            acc[t] = __builtin_amdgcn_mfma_f32_16x16x32_bf16(av, bv, acc[t], 0, 0, 0);
        }
    }

    float s1p[4] = {0.f, 0.f, 0.f, 0.f};
    float s2p[4] = {0.f, 0.f, 0.f, 0.f};
#pragma unroll
    for (int t = 0; t < 8; ++t) {
        float a1v = a[t * 16 + fr];
        float a2v = a[128 + t * 16 + fr];
#pragma unroll
        for (int r = 0; r < 4; ++r) {
            s1p[r] += acc[t][r] * a1v;
            s2p[r] += acc[t][r] * a2v;
        }
    }
#pragma unroll
    for (int r = 0; r < 4; ++r) {
#pragma unroll
        for (int m = 1; m < 16; m <<= 1) {
            s1p[r] += __shfl_xor(s1p[r], m, 64);
            s2p[r] += __shfl_xor(s2p[r], m, 64);
        }
    }
    if (fr == 0) {
#pragma unroll
        for (int r = 0; r < 4; ++r) {
            const int i = i0 + quad * 4 + r;
            s1L2E[i] = s1p[r] * L2E;
            s2L2E[i] = s2p[r] * L2E;
        }
    }

#pragma unroll
    for (int t = 0; t < 8; ++t) {
        short4v hv;
#pragma unroll
        for (int r = 0; r < 4; ++r) hv[r] = f2bf(acc[t][r]);
        *(short4v*)(hT + (size_t)(t * 16 + fr) * NN + i0 + quad * 4) = hv;
    }
}

// ---------- K2: 2-deep counted-vmcnt LDS pipeline, 3 blocks/CU ----------
// R6 structure (verified) with occupancy pushed 2->3 blocks/CU:
// BUFB=25600 x 2 buffers + zbuf = 51.4KB LDS; JSPLIT=4 -> 1024 blocks;
// __launch_bounds__(256,3). Steady state keeps stage t+1 (7 gll) in flight:
// s_waitcnt vmcnt(7) + raw s_barrier (never drains in-loop, T4).
// setprio(1) around compute (T5: 3 blocks/CU gives the scheduler role-split).
// XOR swizzle phys = logical ^ ((row&7)<<4) pre-applied on global sources
// (linear gll dest) + identical XOR on reads (R5/R6-verified).
template<int JSPLIT, bool PARTIAL>
__global__ __launch_bounds__(256, 3) void k2_attn(
        const int* __restrict__ adj, const short* __restrict__ hT,
        const float* __restrict__ s1g, const float* __restrict__ s2g,
        float* __restrict__ pvp, float* __restrict__ zp,
        float* __restrict__ out) {
    constexpr int JW = NN / JSPLIT;
    constexpr int NSTEP = JW / 64;
    constexpr int BUFB = 25600;           // hT 16K | adj 8K | s2 1K | pad
    __shared__ __align__(16) char lds_c[2 * BUFB + 256];

    const int tid = threadIdx.x;
    const int w = tid >> 6;
    const int l = tid & 63;
    const int quad = l >> 4;
    const int fr = l & 15;
    const int rh = w >> 1;
    const int wj = w & 1;
    const int rb = blockIdx.x / JSPLIT;
    const int jb = blockIdx.x % JSPLIT;
    const int r32 = rb * 32;
    const int jbb = jb * JW;

    const float S = s1g[r32 + rh * 16 + fr];   // s1*log2e for this lane's row

    // ---- pre-swizzled per-lane global sources ----
    const char* hsrc[4];
    {
        const char* hbase = (const char*)hT;
#pragma unroll
        for (int p = 0; p < 4; ++p) {
            const int o = p * 4096 + tid * 16;        // LDS-linear offset
            const int row = o >> 7;                   // feature row (128B/row)
            const int colb = o & 127;
            hsrc[p] = hbase + (size_t)row * (NN * 2) + (size_t)jbb * 2
                    + (colb ^ ((row & 7) << 4));
        }
    }
    const char* asrc[2];
    {
        const char* abase = (const char*)adj;
#pragma unroll
        for (int p = 0; p < 2; ++p) {
            const int o = p * 4096 + tid * 16;
            const int row = o >> 8;                   // adj row (256B/row)
            const int colb = o & 255;
            asrc[p] = abase + (size_t)(r32 + row) * (NN * 4) + (size_t)jbb * 4
                    + (colb ^ ((row & 7) << 4));
        }
    }
    // s2 strip source: 1KB window, all lanes (4-wave WAW is benign+uniform)
    const char* csrc = (const char*)s2g + (size_t)jbb * 4 + l * 16;

    auto STAGE = [&](int jt, int buf) {
        jt = (jt < NSTEP) ? jt : NSTEP - 1;           // tail clamp (junk stage)
        char* hd = lds_c + buf * BUFB + w * 1024;
        char* ad = lds_c + buf * BUFB + 16384 + w * 1024;
        char* cd = lds_c + buf * BUFB + 24576;
        const size_t hof = (size_t)jt * 128;
        const size_t aof = (size_t)jt * 256;
#pragma unroll
        for (int p = 0; p < 4; ++p) gll16(hsrc[p] + hof, hd + p * 4096);
#pragma unroll
        for (int p = 0; p < 2; ++p) gll16(asrc[p] + aof, ad + p * 4096);
        gll16(csrc + aof, cd);
    };

    f32x4 acc[8];
#pragma unroll
    for (int t = 0; t < 8; ++t) acc[t] = zero4();
    float zacc = 0.f;

    // prologue: 2 tiles in flight (14 gll/wave)
    STAGE(0, 0); STAGE(1, 1);

    for (int t = 0; t < NSTEP; ++t) {
        const int cur = t & 1;
        // buf `cur` ready once only stage t+1 (7 gll) remains outstanding
        asm volatile("s_waitcnt vmcnt(7)" ::: "memory");
        __builtin_amdgcn_s_barrier();
        __builtin_amdgcn_sched_barrier(0);
        __builtin_amdgcn_s_setprio(1);

        const char* hb = lds_c + cur * BUFB;
        const char* ab = lds_c + cur * BUFB + 16384;
        const float* cb = (const float*)(lds_c + cur * BUFB + 24576);

        const int arow = rh * 16 + fr;
        const unsigned aswz = (unsigned)((arow & 7) << 4);
        const unsigned al = (unsigned)(arow * 256 + wj * 128 + quad * 32);
        const int4v g0 = *(const int4v*)(ab + (al ^ aswz));
        const int4v g1 = *(const int4v*)(ab + ((al + 16) ^ aswz));
        const f32x4 c0 = *(const f32x4*)(cb + wj * 32 + quad * 8);
        const f32x4 c1 = *(const f32x4*)(cb + wj * 32 + quad * 8 + 4);

        short8 pa;
        {
            float zs = 0.f;
#pragma unroll
            for (int e = 0; e < 8; ++e) {
                const float cv = (e < 4) ? c0[e & 3] : c1[e & 3];
                const int gv = (e < 4) ? g0[e & 3] : g1[e & 3];
                const float u = S + cv;                 // (s1+s2)*log2e
                const float tt = fmaxf(u, 0.2f * u);    // leaky-relu in log2 space
                const float p = (gv > 0) ? exp2f(tt) : 0.f;
                zs += p;
                pa[e] = f2bf(p);
            }
            zacc += zs;
        }

#pragma unroll
        for (int t8 = 0; t8 < 8; ++t8) {
            const int hrow = t8 * 16 + fr;
            const short8 bv = *(const short8*)(
                hb + ((unsigned)(hrow * 128 + wj * 64 + quad * 16) ^ ((hrow & 7) << 4)));
            acc[t8] = __builtin_amdgcn_mfma_f32_16x16x32_bf16(pa, bv, acc[t8], 0, 0, 0);
        }

        __builtin_amdgcn_s_setprio(0);
        __builtin_amdgcn_sched_barrier(0);
        asm volatile("" ::: "memory");
        __builtin_amdgcn_s_barrier();                 // all waves done reading buf cur

        STAGE(t + 2, cur);                            // refill the buffer just freed
    }

    asm volatile("s_waitcnt vmcnt(0)" ::: "memory");  // drain junk stages before aliasing
    __syncthreads();

    // ---- reduction (red aliases buffer 0's hT region) ----
    zacc += __shfl_xor(zacc, 16, 64);
    zacc += __shfl_xor(zacc, 32, 64);
    float* zb = (float*)(lds_c + 2 * BUFB);
    if (l < 16) zb[w * 16 + l] = zacc;

    float* red = (float*)lds_c;   // 2 regions x 2048 floats
    if (wj == 1) {
#pragma unroll
        for (int t = 0; t < 8; ++t)
            *(f32x4*)(red + rh * 2048 + t * 256 + l * 4) = acc[t];
    }
    __syncthreads();

    if (wj == 0) {
#pragma unroll
        for (int t = 0; t < 8; ++t)
            acc[t] += *(const f32x4*)(red + rh * 2048 + t * 256 + l * 4);
#pragma unroll
        for (int r = 0; r < 4; ++r) {
            const int irow = quad * 4 + r;
            const float z = zb[rh * 32 + irow] + zb[rh * 32 + 16 + irow];
            const int grow = r32 + rh * 16 + irow;
            if (PARTIAL) {
                if (fr == 0) zp[(size_t)jb * NN + grow] = z;
                float* orow = pvp + ((size_t)jb * NN + grow) * 128;
#pragma unroll
                for (int t = 0; t < 8; ++t) orow[t * 16 + fr] = acc[t][r];
            } else {
                const float inv = 1.0f / z;
                float* orow = out + (size_t)grow * 128;
#pragma unroll
                for (int t = 0; t < 8; ++t) {
                    float v = acc[t][r] * inv;
                    orow[t * 16 + fr] = (v > 0.f) ? v : expm1f(v);
                }
            }
        }
    }
}

// ---------- K3: sum partials, divide by Z, ELU ----------
__global__ __launch_bounds__(256) void k3_fin(
        const float* __restrict__ pvp, const float* __restrict__ zp,
        float* __restrict__ out, int jsplit) {
    const int idx = blockIdx.x * 256 + threadIdx.x;
    const int row = idx >> 5;
    const int c = (idx & 31) << 2;
    f32x4 s = zero4();
    float z = 0.f;
    for (int p = 0; p < jsplit; ++p) {
        s += *(const f32x4*)(pvp + ((size_t)p * NN + row) * 128 + c);
        z += zp[(size_t)p * NN + row];
    }
    const float inv = 1.0f / z;
    f32x4 o;
#pragma unroll
    for (int e = 0; e < 4; ++e) {
        float v = s[e] * inv;
        o[e] = (v > 0.f) ? v : expm1f(v);
    }
    *(f32x4*)(out + (size_t)row * 128 + c) = o;
}

extern "C" void kernel_launch(void* const* d_in, const int* in_sizes, int n_in,
                              void* d_out, int out_size, void* d_ws, size_t ws_size,
                              hipStream_t stream) {
    const float* x   = (const float*)d_in[0];   // 8192 x 256
    const float* W   = (const float*)d_in[1];   // 256 x 128
    const float* a   = (const float*)d_in[2];   // 256
    const int*   adj = (const int*)d_in[3];     // 8192 x 8192
    float* out = (float*)d_out;                 // 8192 x 128

    char* ws = (char*)d_ws;
    const size_t MB = 1024 * 1024;
    short* hT    = (short*)ws;                        // 2 MB
    float* s1L2E = (float*)(ws + 2 * MB);             // 32 KB
    float* s2L2E = (float*)(ws + 2 * MB + 32768);     // 32 KB
    short* WT    = (short*)(ws + 2 * MB + 65536);     // 64 KB
    const size_t base = 2 * MB + 131072;

    auto need = [&](size_t js) {
        return base + js * ((size_t)NN * 128 * 4) + js * ((size_t)NN * 4);
    };
    int jsplit;
    if (ws_size >= need(4)) jsplit = 4;
    else if (ws_size >= need(2)) jsplit = 2;
    else if (ws_size >= need(1)) jsplit = 1;
    else jsplit = 0;

    float* pvp = (float*)(ws + base);
    float* zp  = (float*)(ws + base + (size_t)(jsplit > 0 ? jsplit : 1) * NN * 128 * 4);

    k0_wt<<<128, 256, 0, stream>>>(W, WT);
    k1_h<<<256, 128, 0, stream>>>(x, WT, a, hT, s1L2E, s2L2E);

    if (jsplit == 4) {
        k2_attn<4, true><<<1024, 256, 0, stream>>>(adj, hT, s1L2E, s2L2E, pvp, zp, nullptr);
        k3_fin<<<1024, 256, 0, stream>>>(pvp, zp, out, 4);
    } else if (jsplit == 2) {
        k2_attn<2, true><<<512, 256, 0, stream>>>(adj, hT, s1L2E, s2L2E, pvp, zp, nullptr);
        k3_fin<<<1024, 256, 0, stream>>>(pvp, zp, out, 2);
    } else if (jsplit == 1) {
        k2_attn<1, true><<<256, 256, 0, stream>>>(adj, hT, s1L2E, s2L2E, pvp, zp, nullptr);
        k3_fin<<<1024, 256, 0, stream>>>(pvp, zp, out, 1);
    } else {
        k2_attn<1, false><<<256, 256, 0, stream>>>(adj, hT, s1L2E, s2L2E, nullptr, nullptr, out);
    }
}